// Round 3
// baseline (269.301 us; speedup 1.0000x reference)
//
#include <hip/hip_runtime.h>

#define EMBED 4096
#define NHEADS 32
#define HDIM 128
#define MAXLEN 4096
#define BATCH 8
#define NSPLIT 16

// ---------------- GEMM: out[m][n] = sum_k X[m][k]*W[n][k] + bias[n], m in [0,8) ----
// 256-thread blocks (4 waves), RPW rows per wave. No LDS: x is 128 KB, L2-resident.
template<int RPW>
__device__ __forceinline__ void gemm8_body(const float* __restrict__ X,
                                           const float* __restrict__ W,
                                           const float* __restrict__ bias,
                                           float* __restrict__ out, int n)
{
    const int lane = threadIdx.x & 63;

    float acc[RPW][8];
    #pragma unroll
    for (int j = 0; j < RPW; ++j)
        #pragma unroll
        for (int m = 0; m < 8; ++m) acc[j][m] = 0.f;

    const float* wb = W + (size_t)n * EMBED;

    #pragma unroll 1
    for (int i = 0; i < 16; ++i) {
        int c = i * 256 + lane * 4;
        float4 wv[RPW];
        #pragma unroll
        for (int j = 0; j < RPW; ++j)
            wv[j] = *(const float4*)(wb + (size_t)j * EMBED + c);
        #pragma unroll
        for (int m = 0; m < 8; ++m) {
            float4 xv = *(const float4*)(X + (size_t)m * EMBED + c);
            #pragma unroll
            for (int j = 0; j < RPW; ++j) {
                acc[j][m] += xv.x * wv[j].x + xv.y * wv[j].y
                           + xv.z * wv[j].z + xv.w * wv[j].w;
            }
        }
    }

    #pragma unroll
    for (int j = 0; j < RPW; ++j)
        #pragma unroll
        for (int m = 0; m < 8; ++m) {
            float v = acc[j][m];
            #pragma unroll
            for (int off = 32; off > 0; off >>= 1) v += __shfl_xor(v, off, 64);
            if (lane == 0) out[(size_t)m * EMBED + n + j] = v + bias[n + j];
        }
}

__global__ __launch_bounds__(256)
void qkv_kernel(const float* __restrict__ x,
                const float* __restrict__ Wq, const float* __restrict__ bq,
                const float* __restrict__ Wk, const float* __restrict__ bk,
                const float* __restrict__ Wv, const float* __restrict__ bv,
                float* __restrict__ qkv /* [3][8][4096] */)
{
    const int wave = threadIdx.x >> 6;
    int ng = blockIdx.x * 16 + wave * 4;     // global row among 3*4096
    int proj = ng >> 12;
    int n = ng & 4095;
    const float* W = proj == 0 ? Wq : (proj == 1 ? Wk : Wv);
    const float* b = proj == 0 ? bq : (proj == 1 ? bk : bv);
    float* out = qkv + (size_t)proj * (BATCH * EMBED);
    gemm8_body<4>(x, W, b, out, n);
}

__global__ __launch_bounds__(256)
void out_kernel(const float* __restrict__ attn,
                const float* __restrict__ Wo, const float* __restrict__ bo,
                float* __restrict__ out)
{
    const int wave = threadIdx.x >> 6;
    int n = blockIdx.x * 8 + wave * 2;
    gemm8_body<2>(attn, Wo, bo, out, n);
}

// ------------- flash-decode attention: single-pass online softmax ----------------
// Block = 256 threads = 4 waves = 8 half-wave "groups" of 32 lanes.
// Group g handles keys t = tstart + g + 8*j. Each group keeps a full 128-dim
// accumulator (32 lanes x float4) plus online (m, l) in registers.
__global__ __launch_bounds__(256)
void attn_partial(const float* __restrict__ qkv,
                  const float* __restrict__ kc, const float* __restrict__ vc,
                  const int* __restrict__ clp,
                  float* __restrict__ part_acc,   // [256][NSPLIT][128]
                  float* __restrict__ part_ms)    // [256][NSPLIT][2]
{
    __shared__ float accs[8][HDIM];   // per-group accumulators
    __shared__ float mls[8][2];       // per-group (m, l)

    const int cl = *clp;
    const int T  = cl + 1;
    const int CH = (T + NSPLIT - 1) / NSPLIT;

    const int bh = blockIdx.x & 255;
    const int sp = blockIdx.x >> 8;
    const int b  = bh >> 5;
    const int h  = bh & 31;
    const int tid = threadIdx.x, w = tid >> 6, lane = tid & 63;
    const int half = lane >> 5, col4 = lane & 31;
    const int g = w * 2 + half;

    const int tstart = sp * CH;
    const int tend   = min(T, tstart + CH);

    const float* q    = qkv + (size_t)b * EMBED + h * HDIM;
    const float* knew = qkv + (size_t)BATCH * EMBED     + (size_t)b * EMBED + h * HDIM;
    const float* vnew = qkv + (size_t)2 * BATCH * EMBED + (size_t)b * EMBED + h * HDIM;
    const float* K = kc + (size_t)bh * MAXLEN * HDIM;
    const float* V = vc + (size_t)bh * MAXLEN * HDIM;

    const float scale = 0.08838834764831845f;   // 1/sqrt(128)
    float4 qv = *(const float4*)(q + col4 * 4);
    qv.x *= scale; qv.y *= scale; qv.z *= scale; qv.w *= scale;

    float m = -3.0e38f, l = 0.f;
    float4 acc = make_float4(0.f, 0.f, 0.f, 0.f);

    for (int base = tstart + g; base < tend; base += 32) {
        float4 kv[4], vv[4];
        #pragma unroll
        for (int u = 0; u < 4; ++u) {
            int t = base + u * 8;
            if (t < tend) {
                const float* kp = (t == cl) ? knew : (K + (size_t)t * HDIM);
                const float* vp = (t == cl) ? vnew : (V + (size_t)t * HDIM);
                kv[u] = *(const float4*)(kp + col4 * 4);
                vv[u] = *(const float4*)(vp + col4 * 4);
            }
        }
        #pragma unroll
        for (int u = 0; u < 4; ++u) {
            int t = base + u * 8;
            if (t < tend) {
                float s = qv.x * kv[u].x + qv.y * kv[u].y
                        + qv.z * kv[u].z + qv.w * kv[u].w;
                #pragma unroll
                for (int off = 16; off > 0; off >>= 1) s += __shfl_xor(s, off, 64);
                float mn   = fmaxf(m, s);
                float corr = __expf(m - mn);
                float p    = __expf(s - mn);
                l = l * corr + p;
                acc.x = acc.x * corr + p * vv[u].x;
                acc.y = acc.y * corr + p * vv[u].y;
                acc.z = acc.z * corr + p * vv[u].z;
                acc.w = acc.w * corr + p * vv[u].w;
                m = mn;
            }
        }
    }

    if (col4 == 0) { mls[g][0] = m; mls[g][1] = l; }
    *(float4*)(&accs[g][col4 * 4]) = acc;
    __syncthreads();

    const size_t pidx = (size_t)bh * NSPLIT + sp;
    if (tid < HDIM) {
        float M = mls[0][0];
        #pragma unroll
        for (int i = 1; i < 8; ++i) M = fmaxf(M, mls[i][0]);
        float L = 0.f, o = 0.f;
        #pragma unroll
        for (int i = 0; i < 8; ++i) {
            float wgt = __expf(mls[i][0] - M);
            L += mls[i][1] * wgt;
            o += accs[i][tid] * wgt;
        }
        part_acc[pidx * HDIM + tid] = o;
        if (tid == 0) {
            part_ms[pidx * 2]     = M;
            part_ms[pidx * 2 + 1] = L;
        }
    }
}

__global__ __launch_bounds__(128)
void combine_kernel(const float* __restrict__ part_acc,
                    const float* __restrict__ part_ms,
                    float* __restrict__ attn)
{
    const int bh = blockIdx.x;
    const int d  = threadIdx.x;

    float m[NSPLIT], s[NSPLIT];
    float gmax = -3.0e38f;
    #pragma unroll
    for (int sp = 0; sp < NSPLIT; ++sp) {
        m[sp] = part_ms[((size_t)bh * NSPLIT + sp) * 2];
        s[sp] = part_ms[((size_t)bh * NSPLIT + sp) * 2 + 1];
        gmax  = fmaxf(gmax, m[sp]);
    }
    float total = 0.f, o = 0.f;
    #pragma unroll
    for (int sp = 0; sp < NSPLIT; ++sp) {
        float wgt = __expf(m[sp] - gmax);
        total += s[sp] * wgt;
        o += part_acc[((size_t)bh * NSPLIT + sp) * HDIM + d] * wgt;
    }
    attn[(size_t)bh * HDIM + d] = o / total;
}

extern "C" void kernel_launch(void* const* d_in, const int* in_sizes, int n_in,
                              void* d_out, int out_size, void* d_ws, size_t ws_size,
                              hipStream_t stream) {
    const float* x  = (const float*)d_in[0];
    const float* kc = (const float*)d_in[1];
    const float* vc = (const float*)d_in[2];
    const float* Wq = (const float*)d_in[3];
    const float* bq = (const float*)d_in[4];
    const float* Wk = (const float*)d_in[5];
    const float* bk = (const float*)d_in[6];
    const float* Wv = (const float*)d_in[7];
    const float* bv = (const float*)d_in[8];
    const float* Wo = (const float*)d_in[9];
    const float* bo = (const float*)d_in[10];
    const int* clp  = (const int*)d_in[11];

    float* out      = (float*)d_out;
    float* qkv      = (float*)d_ws;                               // 3*8*4096
    float* attn     = qkv + (size_t)3 * BATCH * EMBED;            // 8*4096
    float* part_acc = attn + (size_t)BATCH * EMBED;               // 256*16*128
    float* part_ms  = part_acc + (size_t)256 * NSPLIT * HDIM;     // 256*16*2

    hipLaunchKernelGGL(qkv_kernel, dim3(768), dim3(256), 0, stream,
                       x, Wq, bq, Wk, bk, Wv, bv, qkv);
    hipLaunchKernelGGL(attn_partial, dim3(256 * NSPLIT), dim3(256), 0, stream,
                       qkv, kc, vc, clp, part_acc, part_ms);
    hipLaunchKernelGGL(combine_kernel, dim3(256), dim3(128), 0, stream,
                       part_acc, part_ms, attn);
    hipLaunchKernelGGL(out_kernel, dim3(512), dim3(256), 0, stream,
                       attn, Wo, bo, out);
}